// Round 9
// baseline (592.839 us; speedup 1.0000x reference)
//
#include <hip/hip_runtime.h>
#include <cstdint>

#define C_DIM 1024
#define T_DIM 2048
#define B_DIM 4
#define FFN_DIM 4096
#define NROWS (B_DIM * T_DIM)                 // 8192 rows (B*T)
#define NELEM ((size_t)NROWS * C_DIM)
#define MB ((size_t)1 << 20)
#define NSEG 32
#define SEGL (T_DIM / NSEG)                   // 64

typedef __bf16 bf16;
typedef __bf16 bf16x4 __attribute__((ext_vector_type(4)));
typedef __bf16 bf16x8 __attribute__((ext_vector_type(8)));
typedef float  floatx4 __attribute__((ext_vector_type(4)));

// async global->LDS, 16B per lane; LDS dest is wave-uniform base + lane*16
#define GLDS(g, l) __builtin_amdgcn_global_load_lds(                          \
    (const __attribute__((address_space(1))) void*)(g),                       \
    (__attribute__((address_space(3))) void*)(l), 16, 0, 0)

// ---------------------------------------------------------------------------
// All 7 weight fp32->bf16 conversions in ONE dispatch.
// ---------------------------------------------------------------------------
struct W7 {
    const float* s[7];
    bf16*        d[7];
    int          cum[8];   // cumulative float4 counts, cum[7] = total
};

__global__ __launch_bounds__(256) void f2b7_kernel(W7 w)
{
    int id = blockIdx.x * 256 + threadIdx.x;
    int seg = 0;
#pragma unroll
    for (int j = 1; j < 7; ++j) if (id >= w.cum[j]) seg = j;
    int i = id - w.cum[seg];
    float4 v = ((const float4*)w.s[seg])[i];
    bf16x4 o = { (bf16)v.x, (bf16)v.y, (bf16)v.z, (bf16)v.w };
    ((bf16x4*)w.d[seg])[i] = o;
}

// ---------------------------------------------------------------------------
// Fused LayerNorm + token-shift mix. One block per row t; computes LN stats
// for rows t and t-1 (recompute, memory-bound), emits bf16 mixed operands.
// hx = LN(x[t-1]) (zero row at t==0, matching reference pad-before-shift).
// ---------------------------------------------------------------------------
template<bool HASV>
__global__ __launch_bounds__(256) void lnmix_kernel(const float* __restrict__ x,
                                                    const float* __restrict__ g,
                                                    const float* __restrict__ b,
                                                    const float* __restrict__ mk,
                                                    const float* __restrict__ mv,
                                                    const float* __restrict__ mr,
                                                    bf16* __restrict__ xk,
                                                    bf16* __restrict__ xv,
                                                    bf16* __restrict__ xr)
{
    int row = blockIdx.x;
    int t   = row & (T_DIM - 1);
    int tid = threadIdx.x;
    size_t i4 = (size_t)row * 256 + tid;

    float4 v  = ((const float4*)x)[i4];
    float4 vp = make_float4(0.f, 0.f, 0.f, 0.f);
    if (t != 0) vp = ((const float4*)x)[i4 - 256];

    float s   = v.x + v.y + v.z + v.w;
    float s2  = v.x * v.x + v.y * v.y + v.z * v.z + v.w * v.w;
    float sp  = vp.x + vp.y + vp.z + vp.w;
    float sp2 = vp.x * vp.x + vp.y * vp.y + vp.z * vp.z + vp.w * vp.w;
    for (int off = 32; off > 0; off >>= 1) {
        s   += __shfl_down(s,   off);
        s2  += __shfl_down(s2,  off);
        sp  += __shfl_down(sp,  off);
        sp2 += __shfl_down(sp2, off);
    }
    __shared__ float red[16];
    int lane = tid & 63, wid = tid >> 6;
    if (lane == 0) { red[wid] = s; red[4 + wid] = s2; red[8 + wid] = sp; red[12 + wid] = sp2; }
    __syncthreads();
    s   = red[0] + red[1] + red[2] + red[3];
    s2  = red[4] + red[5] + red[6] + red[7];
    sp  = red[8] + red[9] + red[10] + red[11];
    sp2 = red[12] + red[13] + red[14] + red[15];

    float mean  = s * (1.0f / C_DIM);
    float inv   = rsqrtf(s2 * (1.0f / C_DIM) - mean * mean + 1e-5f);
    float meanp = sp * (1.0f / C_DIM);
    float invp  = rsqrtf(sp2 * (1.0f / C_DIM) - meanp * meanp + 1e-5f);

    float4 gv = ((const float4*)g)[tid];
    float4 bv = ((const float4*)b)[tid];
    float4 hv, hp;
    hv.x = (v.x - mean) * inv * gv.x + bv.x;
    hv.y = (v.y - mean) * inv * gv.y + bv.y;
    hv.z = (v.z - mean) * inv * gv.z + bv.z;
    hv.w = (v.w - mean) * inv * gv.w + bv.w;
    if (t != 0) {
        hp.x = (vp.x - meanp) * invp * gv.x + bv.x;
        hp.y = (vp.y - meanp) * invp * gv.y + bv.y;
        hp.z = (vp.z - meanp) * invp * gv.z + bv.z;
        hp.w = (vp.w - meanp) * invp * gv.w + bv.w;
    } else {
        hp = make_float4(0.f, 0.f, 0.f, 0.f);
    }

    float4 m1 = ((const float4*)mk)[tid];
    bf16x4 o;
    o.x = (bf16)(hp.x + m1.x * (hv.x - hp.x));
    o.y = (bf16)(hp.y + m1.y * (hv.y - hp.y));
    o.z = (bf16)(hp.z + m1.z * (hv.z - hp.z));
    o.w = (bf16)(hp.w + m1.w * (hv.w - hp.w));
    ((bf16x4*)xk)[i4] = o;

    if (HASV) {
        float4 m2 = ((const float4*)mv)[tid];
        o.x = (bf16)(hp.x + m2.x * (hv.x - hp.x));
        o.y = (bf16)(hp.y + m2.y * (hv.y - hp.y));
        o.z = (bf16)(hp.z + m2.z * (hv.z - hp.z));
        o.w = (bf16)(hp.w + m2.w * (hv.w - hp.w));
        ((bf16x4*)xv)[i4] = o;
    }

    float4 m3 = ((const float4*)mr)[tid];
    o.x = (bf16)(hp.x + m3.x * (hv.x - hp.x));
    o.y = (bf16)(hp.y + m3.y * (hv.y - hp.y));
    o.z = (bf16)(hp.z + m3.z * (hv.z - hp.z));
    o.w = (bf16)(hp.w + m3.w * (hv.w - hp.w));
    ((bf16x4*)xr)[i4] = o;
}

// ---------------------------------------------------------------------------
// bf16 MFMA TN GEMM: Y[M,N] = epi( A[M,K] @ W[N,K]^T ), M = 8192.
// 256x128 tile, BK=64, 512 thr (8 waves, 4m x 2n of 64x64 each).
// ROUND-9: FINE 4-PHASE SCHEDULE (m201 pattern scaled to this geometry).
// Round-8's coarse 2-phase loop hit the documented 2-phase ceiling (691 TF,
// MfmaUtil 27.6%, ~2400cy/tile bubble vs 1240cy MFMA). Per m196/m228e/m218b
// the lever is the fine per-phase interleave + setprio role-split. Each
// K64-tile = 4 phases: {2-6 ds_read + 1-2 GLDS -> s_barrier -> lgkmcnt(0)
// -> setprio(1) 8 MFMA setprio(0) -> s_barrier}. Phase barriers are
// scheduling-only; the single correctness barrier is at tile top (counted
// vmcnt(6): tile t landed, t+1 stays in flight -- round-5 A/B +22%).
// TRIPLE-BUFFERED LDS (mod-3): stage(t+2) writes the buffer read at t-1.
// LDS cell (row r, k-quad q of 32-col subtile) at r*32 + ((q+(r>>1))&3)*8
// ushorts: conflict-free ds_read_b128 (BANK_CONFLICT=0 measured),
// lane-contiguous GLDS dest.
// Grid: N=1024 -> 256 blocks = 1/CU, m-striped XCDs (round-7: FETCH 3.3x
// lower). N=4096 -> 1024 blocks, n-striped (W-heavy).
// Epilogues (runtime, uniform): 0=none 1=sigmoid 2=relu^2 3=X2+acc 4=X2+S*acc
// ---------------------------------------------------------------------------
#define EPI_NONE 0
#define EPI_SIG 1
#define EPI_RELU2 2
#define EPI_ADD 3
#define EPI_SCALEADD 4

struct GemmArgs {
    const bf16* A;
    const bf16* W;
    void*       Y;
    const float* X2;
    const bf16*  S;
    int N, K, epi, outBf16;
};

__global__ __launch_bounds__(512) void gemm_p(GemmArgs pr)
{
    // per-buffer: A 256x64 bf16 = 16384 ushorts (32KB), B 128x64 = 8192 (16KB)
    __shared__ unsigned short As[3 * 16384];   // 96 KB
    __shared__ unsigned short Bs[3 * 8192];    // 48 KB

    int tid = threadIdx.x;
    int lid = blockIdx.x;
    const bf16* PA = pr.A;
    const bf16* PW = pr.W;
    void*       PY = pr.Y;
    const float* PX2 = pr.X2;
    const bf16*  PS  = pr.S;
    int N = pr.N, K = pr.K;
    int epi = pr.epi, obf = pr.outBf16;

    // Tile mapping. HW round-robins blockIdx across XCDs: xcd = lid & 7.
    int ntn = N >> 7;                       // n-tiles: 8 (N=1024) or 32 (4096)
    int m_t, n_t;
    if (ntn == 8) {
        // A-heavy: m-striped XCDs; each XCD owns 4 m-panels x 8 n-tiles.
        int xcd = lid & 7, s = lid >> 3;    // s in [0,32)
        n_t = s & 7;
        m_t = (xcd << 2) | (s >> 3);
    } else {
        // W-heavy: n-striped XCDs; stride 4 n-tiles per XCD.
        int sq = lid >> 3;                  // [0,128)
        n_t = (lid & 7) * 4 + (sq & 3);
        m_t = sq >> 2;
    }
    int m0 = m_t * 256, n0 = n_t * 128;

    int wv = tid >> 6;                      // 0..7
    int ln = tid & 63;

    // staging source: each wave stages 16 rows per chunk; 4 lanes/row.
    int srow = wv * 16 + (ln >> 2);                    // 0..127
    int qsw  = ((ln & 3) - ((srow >> 1) & 3)) & 3;     // rotated k-quad
    const bf16* Ag = PA + (size_t)(m0 + srow) * K + qsw * 8;   // A chunk0
    const bf16* Wg = PW + (size_t)(n0 + srow) * K + qsw * 8;   // B (one chunk)
    size_t rowK128 = (size_t)128 * K;                  // A chunk1 offset

    // wave-uniform LDS staging bases (ushort units)
    unsigned short* AsW = As + wv * 512;
    unsigned short* BsW = Bs + wv * 512;

    // read addressing: wave (wv&3) of 4 m-slots, (wv>>2) of 2 n-slots
    int wm = (wv & 3) * 64, wn = (wv >> 2) * 64;
    int ra0 = wm + (ln & 15);
    int rb0 = wn + (ln & 15);
    int qa  = ln >> 4;
    int abase = ra0 * 32 + (((qa + ((ra0 >> 1) & 3)) & 3) * 8);
    int bbase = rb0 * 32 + (((qa + ((rb0 >> 1) & 3)) & 3) * 8);

    floatx4 acc[4][4] = {};

    // stage tile kt (64 K-cols) into buffer bi: 4 A-GLDS + 2 B-GLDS per wave
#define STAGE_A(kt, bi)                                                       \
    do {                                                                      \
        const bf16* _a = Ag + (size_t)(kt) * 64;                              \
        unsigned short* _d = AsW + (bi) * 16384;                              \
        GLDS(_a,                _d);            /* sub0 chunk0 */             \
        GLDS(_a + rowK128,      _d + 4096);     /* sub0 chunk1 */             \
        GLDS(_a + 32,           _d + 8192);     /* sub1 chunk0 */             \
        GLDS(_a + rowK128 + 32, _d + 12288);    /* sub1 chunk1 */             \
    } while (0)
#define STAGE_B(kt, bi)                                                       \
    do {                                                                      \
        const bf16* _b = Wg + (size_t)(kt) * 64;                              \
        unsigned short* _d = BsW + (bi) * 8192;                               \
        GLDS(_b,      _d);                      /* sub0 */                    \
        GLDS(_b + 32, _d + 4096);               /* sub1 */                    \
    } while (0)

#define MFMA1(ai, bj, i, j)                                                   \
    acc[i][j] = __builtin_amdgcn_mfma_f32_16x16x32_bf16(ai, bj, acc[i][j], 0, 0, 0)

    int nt = K >> 6;                        // 16 (K=1024) or 64 (K=4096)

    // prologue: tiles 0,1 -> buffers 0,1 (12 loads in flight per wave)
    STAGE_A(0, 0); STAGE_B(0, 0);
    STAGE_A(1, 1); STAGE_B(1, 1);

    int bi = 0, bi2 = 2;                    // read buffer, stage buffer
    for (int t = 0; t < nt; ++t) {
        // tile-top: oldest tile's 6 loads landed; t+1's stay in flight.
        if (t < nt - 1) asm volatile("s_waitcnt vmcnt(6)" ::: "memory");
        else            asm volatile("s_waitcnt vmcnt(0)" ::: "memory");
        __builtin_amdgcn_s_barrier();        // correctness: buf[bi] ready,
        __builtin_amdgcn_sched_barrier(0);   // prior tile's reads all done

        const unsigned short* A0 = As + bi * 16384 + abase;
        const unsigned short* B0 = Bs + bi * 8192  + bbase;
        int dost = (t + 2 < nt);
        int tn   = dost ? (t + 2) : 0;       // clamped (never deref'd if !dost)
        const bf16* a2 = Ag + (size_t)tn * 64;
        const bf16* b2 = Wg + (size_t)tn * 64;
        unsigned short* dA = AsW + bi2 * 16384;
        unsigned short* dB = BsW + bi2 * 8192;

        bf16x8 a[4], p, q;

        // ---- P1: sub0, n-half 0 (reads 6, stage 2x A-GLDS) ----
#pragma unroll
        for (int i = 0; i < 4; ++i) a[i] = *(const bf16x8*)(A0 + i * 512);
        p = *(const bf16x8*)(B0);
        q = *(const bf16x8*)(B0 + 512);
        if (dost) { GLDS(a2, dA); GLDS(a2 + rowK128, dA + 4096); }
        __builtin_amdgcn_s_barrier();
        asm volatile("s_waitcnt lgkmcnt(0)" ::: "memory");
        __builtin_amdgcn_sched_barrier(0);   // rule 18
        __builtin_amdgcn_s_setprio(1);
#pragma unroll
        for (int i = 0; i < 4; ++i) { MFMA1(a[i], p, i, 0); MFMA1(a[i], q, i, 1); }
        __builtin_amdgcn_s_setprio(0);
        __builtin_amdgcn_s_barrier();

        // ---- P2: sub0, n-half 1 (reads 2, stage 2x A-GLDS) ----
        p = *(const bf16x8*)(B0 + 1024);
        q = *(const bf16x8*)(B0 + 1536);
        if (dost) { GLDS(a2 + 32, dA + 8192); GLDS(a2 + rowK128 + 32, dA + 12288); }
        __builtin_amdgcn_s_barrier();
        asm volatile("s_waitcnt lgkmcnt(0)" ::: "memory");
        __builtin_amdgcn_sched_barrier(0);
        __builtin_amdgcn_s_setprio(1);
#pragma unroll
        for (int i = 0; i < 4; ++i) { MFMA1(a[i], p, i, 2); MFMA1(a[i], q, i, 3); }
        __builtin_amdgcn_s_setprio(0);
        __builtin_amdgcn_s_barrier();

        // ---- P3: sub1, n-half 0 (reads 6, stage 1x B-GLDS) ----
#pragma unroll
        for (int i = 0; i < 4; ++i) a[i] = *(const bf16x8*)(A0 + 8192 + i * 512);
        p = *(const bf16x8*)(B0 + 4096);
        q = *(const bf16x8*)(B0 + 4096 + 512);
        if (dost) GLDS(b2, dB);
        __builtin_amdgcn_s_barrier();
        asm volatile("s_waitcnt lgkmcnt(0)" ::: "memory");
        __builtin_amdgcn_sched_barrier(0);
        __builtin_amdgcn_s_setprio(1);
#pragma unroll
        for (int i = 0; i < 4; ++i) { MFMA1(a[i], p, i, 0); MFMA1(a[i], q, i, 1); }
        __builtin_amdgcn_s_setprio(0);
        __builtin_amdgcn_s_barrier();

        // ---- P4: sub1, n-half 1 (reads 2, stage 1x B-GLDS) ----
        p = *(const bf16x8*)(B0 + 4096 + 1024);
        q = *(const bf16x8*)(B0 + 4096 + 1536);
        if (dost) GLDS(b2 + 32, dB + 4096);
        __builtin_amdgcn_s_barrier();
        asm volatile("s_waitcnt lgkmcnt(0)" ::: "memory");
        __builtin_amdgcn_sched_barrier(0);
        __builtin_amdgcn_s_setprio(1);
#pragma unroll
        for (int i = 0; i < 4; ++i) { MFMA1(a[i], p, i, 2); MFMA1(a[i], q, i, 3); }
        __builtin_amdgcn_s_setprio(0);
        // no trailing barrier: tile-top barrier of next iter provides it

        bi  = (bi  == 2) ? 0 : bi  + 1;
        bi2 = (bi2 == 2) ? 0 : bi2 + 1;
    }

#undef STAGE_A
#undef STAGE_B
#undef MFMA1

    // C/D layout (m89-verified): col = lane&15, row = (lane>>4)*4 + reg
    int row0 = (ln >> 4) * 4;
    int colb = n0 + wn + (ln & 15);
#pragma unroll
    for (int i = 0; i < 4; ++i) {
        int gm = m0 + wm + i * 16 + row0;
#pragma unroll
        for (int j = 0; j < 4; ++j) {
            int gn = colb + j * 16;
#pragma unroll
            for (int r = 0; r < 4; ++r) {
                size_t idx = (size_t)(gm + r) * N + gn;
                float v = acc[i][j][r];
                if (epi == EPI_SIG)        v = 1.0f / (1.0f + __expf(-v));
                else if (epi == EPI_RELU2) { float t2 = fmaxf(v, 0.0f); v = t2 * t2; }
                else if (epi == EPI_ADD)   v = PX2[idx] + v;
                else if (epi == EPI_SCALEADD) v = PX2[idx] + (float)PS[idx] * v;
                if (obf) ((bf16*)PY)[idx] = (bf16)v;
                else     ((float*)PY)[idx] = v;
            }
        }
    }
}

// ---------------------------------------------------------------------------
// WKV segmented scan (3 passes), log-space stabilized state (aa,bb)*e^pp.
// ---------------------------------------------------------------------------
__global__ __launch_bounds__(256) void wkv_seg(const float* __restrict__ k,
                                               const float* __restrict__ v,
                                               const float* __restrict__ decay,
                                               float* __restrict__ sa,
                                               float* __restrict__ sb,
                                               float* __restrict__ sp)
{
    int idx = blockIdx.x * 256 + threadIdx.x;   // (b*NSEG+seg)*C + c
    int c   = idx & (C_DIM - 1);
    int bs  = idx >> 10;
    int seg = bs & (NSEG - 1);
    int b   = bs >> 5;
    float w = -__expf(decay[c]);
    size_t base = ((size_t)b * T_DIM + (size_t)seg * SEGL) * C_DIM + c;
    float aa = 0.f, bb = 0.f, pp = -1e38f;
    for (int t = 0; t < SEGL; ++t) {
        size_t off = base + (size_t)t * C_DIM;
        float kk = k[off], vv = v[off];
        float ww2 = pp + w;
        float p2  = fmaxf(ww2, kk);
        float e1  = __expf(ww2 - p2);
        float e2  = __expf(kk - p2);
        aa = e1 * aa + e2 * vv;
        bb = e1 * bb + e2;
        pp = p2;
    }
    sa[idx] = aa; sb[idx] = bb; sp[idx] = pp;
}

__global__ __launch_bounds__(256) void wkv_comb(const float* __restrict__ sa,
                                                const float* __restrict__ sb,
                                                const float* __restrict__ sp,
                                                const float* __restrict__ decay,
                                                float* __restrict__ ia,
                                                float* __restrict__ ib,
                                                float* __restrict__ ip)
{
    int idx = blockIdx.x * 256 + threadIdx.x;   // b*C + c
    int c = idx & (C_DIM - 1);
    int b = idx >> 10;
    float wL = -__expf(decay[c]) * (float)SEGL;
    float aa = 0.f, bb = 0.f, pp = -1e38f;
    size_t base = (size_t)b * NSEG * C_DIM + c;
    for (int j = 0; j < NSEG; ++j) {
        size_t o = base + (size_t)j * C_DIM;
        ia[o] = aa; ib[o] = bb; ip[o] = pp;     // incoming state for segment j
        float a_s = sa[o], b_s = sb[o], p_s = sp[o];
        float pd = pp + wL;
        float pn = fmaxf(pd, p_s);
        float e1 = __expf(pd - pn);
        float e2 = __expf(p_s - pn);
        aa = e1 * aa + e2 * a_s;
        bb = e1 * bb + e2 * b_s;
        pp = pn;
    }
}

__global__ __launch_bounds__(256) void wkv_out(const float* __restrict__ k,
                                               const float* __restrict__ v,
                                               const bf16* __restrict__ sr,
                                               const float* __restrict__ decay,
                                               const float* __restrict__ first,
                                               const float* __restrict__ ia,
                                               const float* __restrict__ ib,
                                               const float* __restrict__ ip,
                                               bf16* __restrict__ out)
{
    int idx = blockIdx.x * 256 + threadIdx.x;   // (b*NSEG+seg)*C + c
    int c   = idx & (C_DIM - 1);
    int bs  = idx >> 10;
    int seg = bs & (NSEG - 1);
    int b   = bs >> 5;
    float w = -__expf(decay[c]);
    float u = first[c];
    float aa = ia[idx], bb = ib[idx], pp = ip[idx];
    size_t base = ((size_t)b * T_DIM + (size_t)seg * SEGL) * C_DIM + c;
    for (int t = 0; t < SEGL; ++t) {
        size_t off = base + (size_t)t * C_DIM;
        float kk = k[off], vv = v[off];
        float ww = u + kk;
        float p  = fmaxf(pp, ww);
        float e1 = __expf(pp - p);
        float e2 = __expf(ww - p);
        float o  = (e1 * aa + e2 * vv) / (e1 * bb + e2);
        out[off] = (bf16)((float)sr[off] * o);
        float ww2 = pp + w;
        float p2  = fmaxf(ww2, kk);
        float e1b = __expf(ww2 - p2);
        float e2b = __expf(kk - p2);
        aa = e1b * aa + e2b * vv;
        bb = e1b * bb + e2b;
        pp = p2;
    }
}

// ---------------------------------------------------------------------------
// Orchestration. Workspace (byte offsets, 173 MiB peak):
//   [0,26M)    bf16 weights
//   [26,74M)   bf16 acts: xk xv xr -> rwkv | xk2 xr2 sr2
//   [74,170M)  fp32 k (32M), v (32M), sr_b bf16 (16M @138M), kk_b (64M @106M)
//   [170,173M) WKV scan scratch: 6 x 512 KiB
// ---------------------------------------------------------------------------
extern "C" void kernel_launch(void* const* d_in, const int* in_sizes, int n_in,
                              void* d_out, int out_size, void* d_ws, size_t ws_size,
                              hipStream_t stream)
{
    const float* x          = (const float*)d_in[0];
    const float* ln1_w      = (const float*)d_in[1];
    const float* ln1_b      = (const float*)d_in[2];
    const float* ln2_w      = (const float*)d_in[3];
    const float* ln2_b      = (const float*)d_in[4];
    const float* time_decay = (const float*)d_in[5];
    const float* time_first = (const float*)d_in[6];
    const float* tmk        = (const float*)d_in[7];
    const float* tmv        = (const float*)d_in[8];
    const float* tmr        = (const float*)d_in[9];
    const float* att_kw     = (const float*)d_in[10];
    const float* att_vw     = (const float*)d_in[11];
    const float* att_rw     = (const float*)d_in[12];
    const float* att_ow     = (const float*)d_in[13];
    const float* f_tmk      = (const float*)d_in[14];
    const float* f_tmr      = (const float*)d_in[15];
    const float* f_kw       = (const float*)d_in[16];
    const float* f_rw       = (const float*)d_in[17];
    const float* f_vw       = (const float*)d_in[18];
    float* out = (float*)d_out;

    char* W8 = (char*)d_ws;
    bf16* kw_b  = (bf16*)(W8 + 0 * MB);
    bf16* vw_b  = (bf16*)(W8 + 2 * MB);
    bf16* rw_b  = (bf16*)(W8 + 4 * MB);
    bf16* ow_b  = (bf16*)(W8 + 6 * MB);
    bf16* fkw_b = (bf16*)(W8 + 8 * MB);
    bf16* frw_b = (bf16*)(W8 + 16 * MB);
    bf16* fvw_b = (bf16*)(W8 + 18 * MB);

    bf16*  xk_b   = (bf16*)(W8 + 26 * MB);
    bf16*  xv_b   = (bf16*)(W8 + 42 * MB);
    bf16*  xr_b   = (bf16*)(W8 + 58 * MB);
    bf16*  rwkv_b = xk_b;
    bf16*  xk2_b  = (bf16*)(W8 + 26 * MB);
    bf16*  xr2_b  = (bf16*)(W8 + 42 * MB);
    bf16*  sr2_b  = (bf16*)(W8 + 58 * MB);
    float* kbuf   = (float*)(W8 + 74 * MB);
    float* vbuf   = (float*)(W8 + 106 * MB);
    bf16*  srb_b  = (bf16*)(W8 + 138 * MB);     // 16 MiB
    bf16*  kk_b   = (bf16*)(W8 + 106 * MB);     // 64 MiB, overlaps vbuf; kk is
    // written only AFTER wkv_out has consumed kbuf/vbuf (ChannelMix phase).

    size_t KB512 = (size_t)512 * 1024;
    float* sc_a = (float*)(W8 + 170 * MB);
    float* sc_b = (float*)(W8 + 170 * MB + 1 * KB512);
    float* sc_p = (float*)(W8 + 170 * MB + 2 * KB512);
    float* in_a = (float*)(W8 + 170 * MB + 3 * KB512);
    float* in_b = (float*)(W8 + 170 * MB + 4 * KB512);
    float* in_p = (float*)(W8 + 170 * MB + 5 * KB512);

    // single-dispatch weight conversion
    int nC4 = C_DIM * C_DIM / 4, nF4 = FFN_DIM * C_DIM / 4;
    W7 w7;
    const float* srcs[7] = { att_kw, att_vw, att_rw, att_ow, f_kw, f_rw, f_vw };
    bf16*        dsts[7] = { kw_b, vw_b, rw_b, ow_b, fkw_b, frw_b, fvw_b };
    int          cnts[7] = { nC4, nC4, nC4, nC4, nF4, nC4, nF4 };
    int cum = 0;
    for (int i = 0; i < 7; ++i) { w7.s[i] = srcs[i]; w7.d[i] = dsts[i]; w7.cum[i] = cum; cum += cnts[i]; }
    w7.cum[7] = cum;                                   // 3407872, /256 = 13312
    f2b7_kernel<<<cum / 256, 256, 0, stream>>>(w7);

    int segGrid = B_DIM * NSEG * C_DIM / 256;   // 512

    auto launch = [&](const bf16* A, const bf16* W, void* Y, const float* X2,
                      const bf16* S, int N, int K, int epi, int obf) {
        GemmArgs p; p.A = A; p.W = W; p.Y = Y; p.X2 = X2; p.S = S;
        p.N = N; p.K = K; p.epi = epi; p.outBf16 = obf;
        int grid = (NROWS / 256) * (N / 128);
        gemm_p<<<grid, 512, 0, stream>>>(p);
    };

    // --- TimeMix ---
    lnmix_kernel<true><<<NROWS, 256, 0, stream>>>(x, ln1_w, ln1_b, tmk, tmv, tmr,
                                                  xk_b, xv_b, xr_b);
    launch(xk_b, kw_b, kbuf,  nullptr, nullptr, C_DIM, C_DIM, EPI_NONE, 0);
    launch(xv_b, vw_b, vbuf,  nullptr, nullptr, C_DIM, C_DIM, EPI_NONE, 0);
    launch(xr_b, rw_b, srb_b, nullptr, nullptr, C_DIM, C_DIM, EPI_SIG,  1);
    wkv_seg<<<segGrid, 256, 0, stream>>>(kbuf, vbuf, time_decay, sc_a, sc_b, sc_p);
    wkv_comb<<<B_DIM * C_DIM / 256, 256, 0, stream>>>(sc_a, sc_b, sc_p, time_decay, in_a, in_b, in_p);
    wkv_out<<<segGrid, 256, 0, stream>>>(kbuf, vbuf, srb_b, time_decay, time_first,
                                         in_a, in_b, in_p, rwkv_b);
    launch(rwkv_b, ow_b, out, x, nullptr, C_DIM, C_DIM, EPI_ADD, 0);

    // --- ChannelMix ---
    lnmix_kernel<false><<<NROWS, 256, 0, stream>>>(out, ln2_w, ln2_b, f_tmk, nullptr, f_tmr,
                                                   xk2_b, nullptr, xr2_b);
    launch(xr2_b, frw_b, sr2_b, nullptr, nullptr, C_DIM,   C_DIM, EPI_SIG,   1);
    launch(xk2_b, fkw_b, kk_b,  nullptr, nullptr, FFN_DIM, C_DIM, EPI_RELU2, 1);
    launch(kk_b,  fvw_b, out,   out,     sr2_b,   C_DIM, FFN_DIM, EPI_SCALEADD, 0);
}

// Round 10
// 528.654 us; speedup vs baseline: 1.1214x; 1.1214x over previous
//
#include <hip/hip_runtime.h>
#include <cstdint>

#define C_DIM 1024
#define T_DIM 2048
#define B_DIM 4
#define FFN_DIM 4096
#define NROWS (B_DIM * T_DIM)                 // 8192 rows (B*T)
#define NELEM ((size_t)NROWS * C_DIM)
#define MB ((size_t)1 << 20)
#define NSEG 32
#define SEGL (T_DIM / NSEG)                   // 64

typedef __bf16 bf16;
typedef __bf16 bf16x4 __attribute__((ext_vector_type(4)));
typedef __bf16 bf16x8 __attribute__((ext_vector_type(8)));
typedef float  floatx4 __attribute__((ext_vector_type(4)));

// async global->LDS, 16B per lane; LDS dest is wave-uniform base + lane*16
#define GLDS(g, l) __builtin_amdgcn_global_load_lds(                          \
    (const __attribute__((address_space(1))) void*)(g),                       \
    (__attribute__((address_space(3))) void*)(l), 16, 0, 0)

// ---------------------------------------------------------------------------
// All 7 weight fp32->bf16 conversions in ONE dispatch.
// ---------------------------------------------------------------------------
struct W7 {
    const float* s[7];
    bf16*        d[7];
    int          cum[8];   // cumulative float4 counts, cum[7] = total
};

__global__ __launch_bounds__(256) void f2b7_kernel(W7 w)
{
    int id = blockIdx.x * 256 + threadIdx.x;
    int seg = 0;
#pragma unroll
    for (int j = 1; j < 7; ++j) if (id >= w.cum[j]) seg = j;
    int i = id - w.cum[seg];
    float4 v = ((const float4*)w.s[seg])[i];
    bf16x4 o = { (bf16)v.x, (bf16)v.y, (bf16)v.z, (bf16)v.w };
    ((bf16x4*)w.d[seg])[i] = o;
}

// ---------------------------------------------------------------------------
// Fused LayerNorm + token-shift mix. One block per row t; computes LN stats
// for rows t and t-1 (recompute, memory-bound), emits bf16 mixed operands.
// hx = LN(x[t-1]) (zero row at t==0, matching reference pad-before-shift).
// ---------------------------------------------------------------------------
template<bool HASV>
__global__ __launch_bounds__(256) void lnmix_kernel(const float* __restrict__ x,
                                                    const float* __restrict__ g,
                                                    const float* __restrict__ b,
                                                    const float* __restrict__ mk,
                                                    const float* __restrict__ mv,
                                                    const float* __restrict__ mr,
                                                    bf16* __restrict__ xk,
                                                    bf16* __restrict__ xv,
                                                    bf16* __restrict__ xr)
{
    int row = blockIdx.x;
    int t   = row & (T_DIM - 1);
    int tid = threadIdx.x;
    size_t i4 = (size_t)row * 256 + tid;

    float4 v  = ((const float4*)x)[i4];
    float4 vp = make_float4(0.f, 0.f, 0.f, 0.f);
    if (t != 0) vp = ((const float4*)x)[i4 - 256];

    float s   = v.x + v.y + v.z + v.w;
    float s2  = v.x * v.x + v.y * v.y + v.z * v.z + v.w * v.w;
    float sp  = vp.x + vp.y + vp.z + vp.w;
    float sp2 = vp.x * vp.x + vp.y * vp.y + vp.z * vp.z + vp.w * vp.w;
    for (int off = 32; off > 0; off >>= 1) {
        s   += __shfl_down(s,   off);
        s2  += __shfl_down(s2,  off);
        sp  += __shfl_down(sp,  off);
        sp2 += __shfl_down(sp2, off);
    }
    __shared__ float red[16];
    int lane = tid & 63, wid = tid >> 6;
    if (lane == 0) { red[wid] = s; red[4 + wid] = s2; red[8 + wid] = sp; red[12 + wid] = sp2; }
    __syncthreads();
    s   = red[0] + red[1] + red[2] + red[3];
    s2  = red[4] + red[5] + red[6] + red[7];
    sp  = red[8] + red[9] + red[10] + red[11];
    sp2 = red[12] + red[13] + red[14] + red[15];

    float mean  = s * (1.0f / C_DIM);
    float inv   = rsqrtf(s2 * (1.0f / C_DIM) - mean * mean + 1e-5f);
    float meanp = sp * (1.0f / C_DIM);
    float invp  = rsqrtf(sp2 * (1.0f / C_DIM) - meanp * meanp + 1e-5f);

    float4 gv = ((const float4*)g)[tid];
    float4 bv = ((const float4*)b)[tid];
    float4 hv, hp;
    hv.x = (v.x - mean) * inv * gv.x + bv.x;
    hv.y = (v.y - mean) * inv * gv.y + bv.y;
    hv.z = (v.z - mean) * inv * gv.z + bv.z;
    hv.w = (v.w - mean) * inv * gv.w + bv.w;
    if (t != 0) {
        hp.x = (vp.x - meanp) * invp * gv.x + bv.x;
        hp.y = (vp.y - meanp) * invp * gv.y + bv.y;
        hp.z = (vp.z - meanp) * invp * gv.z + bv.z;
        hp.w = (vp.w - meanp) * invp * gv.w + bv.w;
    } else {
        hp = make_float4(0.f, 0.f, 0.f, 0.f);
    }

    float4 m1 = ((const float4*)mk)[tid];
    bf16x4 o;
    o.x = (bf16)(hp.x + m1.x * (hv.x - hp.x));
    o.y = (bf16)(hp.y + m1.y * (hv.y - hp.y));
    o.z = (bf16)(hp.z + m1.z * (hv.z - hp.z));
    o.w = (bf16)(hp.w + m1.w * (hv.w - hp.w));
    ((bf16x4*)xk)[i4] = o;

    if (HASV) {
        float4 m2 = ((const float4*)mv)[tid];
        o.x = (bf16)(hp.x + m2.x * (hv.x - hp.x));
        o.y = (bf16)(hp.y + m2.y * (hv.y - hp.y));
        o.z = (bf16)(hp.z + m2.z * (hv.z - hp.z));
        o.w = (bf16)(hp.w + m2.w * (hv.w - hp.w));
        ((bf16x4*)xv)[i4] = o;
    }

    float4 m3 = ((const float4*)mr)[tid];
    o.x = (bf16)(hp.x + m3.x * (hv.x - hp.x));
    o.y = (bf16)(hp.y + m3.y * (hv.y - hp.y));
    o.z = (bf16)(hp.z + m3.z * (hv.z - hp.z));
    o.w = (bf16)(hp.w + m3.w * (hv.w - hp.w));
    ((bf16x4*)xr)[i4] = o;
}

// ---------------------------------------------------------------------------
// gemm_p: round-8 kernel VERBATIM (best measured: 539.8us total).
// 256x128 tile, BK=64, 512 thr (8 waves, 4m x 2n of 64x64), triple-buffered
// LDS (mod-3), coarse 2-subtile consume, counted vmcnt(6) at tile top.
// Round-9's fine 4-phase REGRESSED (99->111us): with 1 block/CU the extra
// per-phase all-wave barriers have nothing to overlap with. Reverted.
// Grid: N=1024 -> 256 blocks, m-striped XCDs (round-7: FETCH 3.3x lower).
// N=4096 -> 1024 blocks, n-striped.
// ---------------------------------------------------------------------------
#define EPI_NONE 0
#define EPI_SIG 1
#define EPI_RELU2 2
#define EPI_ADD 3
#define EPI_SCALEADD 4

struct GemmArgs {
    const bf16* A;
    const bf16* W;
    void*       Y;
    const float* X2;
    const bf16*  S;
    int N, K, epi, outBf16;
};

__global__ __launch_bounds__(512) void gemm_p(GemmArgs pr)
{
    // per-buffer: A 256x64 bf16 = 16384 ushorts (32KB), B 128x64 = 8192 (16KB)
    __shared__ unsigned short As[3 * 16384];   // 96 KB
    __shared__ unsigned short Bs[3 * 8192];    // 48 KB

    int tid = threadIdx.x;
    int lid = blockIdx.x;
    const bf16* PA = pr.A;
    const bf16* PW = pr.W;
    void*       PY = pr.Y;
    const float* PX2 = pr.X2;
    const bf16*  PS  = pr.S;
    int N = pr.N, K = pr.K;
    int epi = pr.epi, obf = pr.outBf16;

    // Tile mapping. HW round-robins blockIdx across XCDs: xcd = lid & 7.
    int ntn = N >> 7;                       // n-tiles: 8 (N=1024) or 32 (4096)
    int m_t, n_t;
    if (ntn == 8) {
        int xcd = lid & 7, s = lid >> 3;    // s in [0,32)
        n_t = s & 7;
        m_t = (xcd << 2) | (s >> 3);
    } else {
        int sq = lid >> 3;                  // [0,128)
        n_t = (lid & 7) * 4 + (sq & 3);
        m_t = sq >> 2;
    }
    int m0 = m_t * 256, n0 = n_t * 128;

    int wv = tid >> 6;                      // 0..7
    int ln = tid & 63;

    int srow = wv * 16 + (ln >> 2);                    // 0..127
    int qsw  = ((ln & 3) - ((srow >> 1) & 3)) & 3;     // rotated k-quad
    const bf16* Ag = PA + (size_t)(m0 + srow) * K + qsw * 8;
    const bf16* Wg = PW + (size_t)(n0 + srow) * K + qsw * 8;
    size_t rowK128 = (size_t)128 * K;

    unsigned short* AsW = As + wv * 512;
    unsigned short* BsW = Bs + wv * 512;

    int wm = (wv & 3) * 64, wn = (wv >> 2) * 64;
    int ra0 = wm + (ln & 15);
    int rb0 = wn + (ln & 15);
    int qa  = ln >> 4;
    int abase = ra0 * 32 + (((qa + ((ra0 >> 1) & 3)) & 3) * 8);
    int bbase = rb0 * 32 + (((qa + ((rb0 >> 1) & 3)) & 3) * 8);

    floatx4 acc[4][4] = {};

#define STAGE_A(kt, bi)                                                       \
    do {                                                                      \
        const bf16* _a = Ag + (size_t)(kt) * 64;                              \
        unsigned short* _d = AsW + (bi) * 16384;                              \
        GLDS(_a,                _d);                                          \
        GLDS(_a + rowK128,      _d + 4096);                                   \
        GLDS(_a + 32,           _d + 8192);                                   \
        GLDS(_a + rowK128 + 32, _d + 12288);                                  \
    } while (0)
#define STAGE_B(kt, bi)                                                       \
    do {                                                                      \
        const bf16* _b = Wg + (size_t)(kt) * 64;                              \
        unsigned short* _d = BsW + (bi) * 8192;                               \
        GLDS(_b,      _d);                                                    \
        GLDS(_b + 32, _d + 4096);                                             \
    } while (0)

#define MFMA16(a, b)                                                          \
    do {                                                                      \
        _Pragma("unroll")                                                     \
        for (int i = 0; i < 4; ++i)                                           \
            _Pragma("unroll")                                                 \
            for (int j = 0; j < 4; ++j)                                       \
                acc[i][j] = __builtin_amdgcn_mfma_f32_16x16x32_bf16(          \
                    a[i], b[j], acc[i][j], 0, 0, 0);                          \
    } while (0)

    int nt = K >> 6;                        // 16 (K=1024) or 64 (K=4096)

    STAGE_A(0, 0); STAGE_B(0, 0);
    STAGE_A(1, 1); STAGE_B(1, 1);

    int bi = 0, bi2 = 2;                    // read buffer, stage buffer
    for (int t = 0; t < nt; ++t) {
        if (t < nt - 1) asm volatile("s_waitcnt vmcnt(6)" ::: "memory");
        else            asm volatile("s_waitcnt vmcnt(0)" ::: "memory");
        __builtin_amdgcn_s_barrier();        // all waves: tile t landed,
        __builtin_amdgcn_sched_barrier(0);   // and t-1 reads fully done

        const unsigned short* A0 = As + bi * 16384 + abase;
        const unsigned short* B0 = Bs + bi * 8192  + bbase;
        int dost = (t + 2 < nt);

        bf16x8 a[4], b[4];
#pragma unroll
        for (int i = 0; i < 4; ++i) a[i] = *(const bf16x8*)(A0 + i * 512);
#pragma unroll
        for (int j = 0; j < 4; ++j) b[j] = *(const bf16x8*)(B0 + j * 512);
        if (dost) STAGE_A(t + 2, bi2);
        asm volatile("s_waitcnt lgkmcnt(0)" ::: "memory");
        __builtin_amdgcn_sched_barrier(0);   // rule 18
        MFMA16(a, b);

#pragma unroll
        for (int i = 0; i < 4; ++i) a[i] = *(const bf16x8*)(A0 + 8192 + i * 512);
#pragma unroll
        for (int j = 0; j < 4; ++j) b[j] = *(const bf16x8*)(B0 + 4096 + j * 512);
        if (dost) STAGE_B(t + 2, bi2);
        asm volatile("s_waitcnt lgkmcnt(0)" ::: "memory");
        __builtin_amdgcn_sched_barrier(0);
        MFMA16(a, b);

        bi  = (bi  == 2) ? 0 : bi  + 1;
        bi2 = (bi2 == 2) ? 0 : bi2 + 1;
    }

#undef STAGE_A
#undef STAGE_B
#undef MFMA16

    int row0 = (ln >> 4) * 4;
    int colb = n0 + wn + (ln & 15);
#pragma unroll
    for (int i = 0; i < 4; ++i) {
        int gm = m0 + wm + i * 16 + row0;
#pragma unroll
        for (int j = 0; j < 4; ++j) {
            int gn = colb + j * 16;
#pragma unroll
            for (int r = 0; r < 4; ++r) {
                size_t idx = (size_t)(gm + r) * N + gn;
                float v = acc[i][j][r];
                if (epi == EPI_SIG)        v = 1.0f / (1.0f + __expf(-v));
                else if (epi == EPI_RELU2) { float t2 = fmaxf(v, 0.0f); v = t2 * t2; }
                else if (epi == EPI_ADD)   v = PX2[idx] + v;
                else if (epi == EPI_SCALEADD) v = PX2[idx] + (float)PS[idx] * v;
                if (obf) ((bf16*)PY)[idx] = (bf16)v;
                else     ((float*)PY)[idx] = v;
            }
        }
    }
}

// ---------------------------------------------------------------------------
// gemm_w: 256x256 tile, BK=64, 512 thr (8 waves, 2m x 4n of 128x64 each),
// double-buffered 128KB LDS. FFN-up only (N=4096 -> 512 blocks, n-striped).
// Rationale (round-9 budget): staging bytes per FLOP drop 11.7 -> 7.6
// B/KFLOP vs 256x128, MFMA:ds_read rises 2.0 -> 2.7 (m201's geometry).
// Coarse schedule per K64-tile: stage(t+1) at top -> 2 x {12 ds_read +
// lgkmcnt + 32 MFMA} -> vmcnt(0) (issue-to-wait cover = full tile compute,
// unlike round-3's 100cy) -> ONE barrier (orders stage-into-read-buffer).
// Same proven swizzle: cell(row r, quad q) at r*32 + ((q+((r>>1)&3))&3)*8.
// ---------------------------------------------------------------------------
__global__ __launch_bounds__(512) void gemm_w(GemmArgs pr)
{
    // per-buffer: A 256x64 = 16384 ushorts (32KB), B 256x64 = 16384 (32KB)
    __shared__ unsigned short As[2 * 16384];   // 64 KB
    __shared__ unsigned short Bs[2 * 16384];   // 64 KB

    int tid = threadIdx.x;
    int lid = blockIdx.x;
    const bf16* PA = pr.A;
    const bf16* PW = pr.W;
    void*       PY = pr.Y;
    int N = pr.N, K = pr.K;
    int epi = pr.epi, obf = pr.outBf16;

    // N=4096: 16 n-tiles, n-striped XCDs (2 per XCD); grid 512.
    int sq  = lid >> 3;                     // [0,64)
    int n_t = (lid & 7) * 2 + (sq & 1);
    int m_t = sq >> 1;                      // [0,32)
    int m0 = m_t * 256, n0 = n_t * 256;

    int wv = tid >> 6;                      // 0..7
    int ln = tid & 63;

    int srow = wv * 16 + (ln >> 2);                    // 0..127
    int qsw  = ((ln & 3) - ((srow >> 1) & 3)) & 3;
    const bf16* Ag = PA + (size_t)(m0 + srow) * K + qsw * 8;
    const bf16* Wg = PW + (size_t)(n0 + srow) * K + qsw * 8;
    size_t rowK128 = (size_t)128 * K;

    unsigned short* AsW = As + wv * 512;
    unsigned short* BsW = Bs + wv * 512;

    // wave: m-slot (wv>>2) of 2 x 128 rows; n-slot (wv&3) of 4 x 64 cols
    int wm = (wv >> 2) * 128, wn = (wv & 3) * 64;
    int ra0 = wm + (ln & 15);
    int rb0 = wn + (ln & 15);
    int qa  = ln >> 4;
    int abase = ra0 * 32 + (((qa + ((ra0 >> 1) & 3)) & 3) * 8);
    int bbase = rb0 * 32 + (((qa + ((rb0 >> 1) & 3)) & 3) * 8);

    floatx4 acc[8][4] = {};

    // stage tile kt into buffer bi: 4 A-GLDS + 4 B-GLDS per wave (64KB total)
#define WSTAGE(kt, bi)                                                        \
    do {                                                                      \
        const bf16* _a = Ag + (size_t)(kt) * 64;                              \
        const bf16* _b = Wg + (size_t)(kt) * 64;                              \
        unsigned short* _dA = AsW + (bi) * 16384;                             \
        unsigned short* _dB = BsW + (bi) * 16384;                             \
        GLDS(_a,                _dA);           /* A sub0 rows 0-127  */      \
        GLDS(_a + rowK128,      _dA + 4096);    /* A sub0 rows 128-255*/      \
        GLDS(_a + 32,           _dA + 8192);    /* A sub1 rows 0-127  */      \
        GLDS(_a + rowK128 + 32, _dA + 12288);   /* A sub1 rows 128-255*/      \
        GLDS(_b,                _dB);                                         \
        GLDS(_b + rowK128,      _dB + 4096);                                  \
        GLDS(_b + 32,           _dB + 8192);                                  \
        GLDS(_b + rowK128 + 32, _dB + 12288);                                 \
    } while (0)

    int nt = K >> 6;                        // 16 for K=1024

    WSTAGE(0, 0);
    asm volatile("s_waitcnt vmcnt(0)" ::: "memory");
    __builtin_amdgcn_s_barrier();
    __builtin_amdgcn_sched_barrier(0);

    for (int t = 0; t < nt; ++t) {
        int bi = t & 1;
        if (t + 1 < nt) WSTAGE(t + 1, bi ^ 1);     // 8 GLDS fly under compute

        const unsigned short* A0 = As + bi * 16384 + abase;
        const unsigned short* B0 = Bs + bi * 16384 + bbase;

#pragma unroll
        for (int s = 0; s < 2; ++s) {
            bf16x8 a[8], b[4];
#pragma unroll
            for (int i = 0; i < 8; ++i) a[i] = *(const bf16x8*)(A0 + s * 8192 + i * 512);
#pragma unroll
            for (int j = 0; j < 4; ++j) b[j] = *(const bf16x8*)(B0 + s * 8192 + j * 512);
            asm volatile("s_waitcnt lgkmcnt(0)" ::: "memory");
            __builtin_amdgcn_sched_barrier(0);     // rule 18
#pragma unroll
            for (int i = 0; i < 8; ++i)
#pragma unroll
                for (int j = 0; j < 4; ++j)
                    acc[i][j] = __builtin_amdgcn_mfma_f32_16x16x32_bf16(
                        a[i], b[j], acc[i][j], 0, 0, 0);
        }

        // next tile's loads landed (issued a full tile ago); all waves done
        // reading buf[bi] before t+1 stages into it.
        asm volatile("s_waitcnt vmcnt(0)" ::: "memory");
        __builtin_amdgcn_s_barrier();
        __builtin_amdgcn_sched_barrier(0);
    }
#undef WSTAGE

    int row0 = (ln >> 4) * 4;
    int colb = n0 + wn + (ln & 15);
#pragma unroll
    for (int i = 0; i < 8; ++i) {
        int gm = m0 + wm + i * 16 + row0;
#pragma unroll
        for (int j = 0; j < 4; ++j) {
            int gn = colb + j * 16;
#pragma unroll
            for (int r = 0; r < 4; ++r) {
                size_t idx = (size_t)(gm + r) * N + gn;
                float v = acc[i][j][r];
                if (epi == EPI_RELU2) { float t2 = fmaxf(v, 0.0f); v = t2 * t2; }
                else if (epi == EPI_SIG) v = 1.0f / (1.0f + __expf(-v));
                if (obf) ((bf16*)PY)[idx] = (bf16)v;
                else     ((float*)PY)[idx] = v;
            }
        }
    }
}

// ---------------------------------------------------------------------------
// WKV segmented scan (3 passes), log-space stabilized state (aa,bb)*e^pp.
// ---------------------------------------------------------------------------
__global__ __launch_bounds__(256) void wkv_seg(const float* __restrict__ k,
                                               const float* __restrict__ v,
                                               const float* __restrict__ decay,
                                               float* __restrict__ sa,
                                               float* __restrict__ sb,
                                               float* __restrict__ sp)
{
    int idx = blockIdx.x * 256 + threadIdx.x;   // (b*NSEG+seg)*C + c
    int c   = idx & (C_DIM - 1);
    int bs  = idx >> 10;
    int seg = bs & (NSEG - 1);
    int b   = bs >> 5;
    float w = -__expf(decay[c]);
    size_t base = ((size_t)b * T_DIM + (size_t)seg * SEGL) * C_DIM + c;
    float aa = 0.f, bb = 0.f, pp = -1e38f;
    for (int t = 0; t < SEGL; ++t) {
        size_t off = base + (size_t)t * C_DIM;
        float kk = k[off], vv = v[off];
        float ww2 = pp + w;
        float p2  = fmaxf(ww2, kk);
        float e1  = __expf(ww2 - p2);
        float e2  = __expf(kk - p2);
        aa = e1 * aa + e2 * vv;
        bb = e1 * bb + e2;
        pp = p2;
    }
    sa[idx] = aa; sb[idx] = bb; sp[idx] = pp;
}

__global__ __launch_bounds__(256) void wkv_comb(const float* __restrict__ sa,
                                                const float* __restrict__ sb,
                                                const float* __restrict__ sp,
                                                const float* __restrict__ decay,
                                                float* __restrict__ ia,
                                                float* __restrict__ ib,
                                                float* __restrict__ ip)
{
    int idx = blockIdx.x * 256 + threadIdx.x;   // b*C + c
    int c = idx & (C_DIM - 1);
    int b = idx >> 10;
    float wL = -__expf(decay[c]) * (float)SEGL;
    float aa = 0.f, bb = 0.f, pp = -1e38f;
    size_t base = (size_t)b * NSEG * C_DIM + c;
    for (int j = 0; j < NSEG; ++j) {
        size_t o = base + (size_t)j * C_DIM;
        ia[o] = aa; ib[o] = bb; ip[o] = pp;     // incoming state for segment j
        float a_s = sa[o], b_s = sb[o], p_s = sp[o];
        float pd = pp + wL;
        float pn = fmaxf(pd, p_s);
        float e1 = __expf(pd - pn);
        float e2 = __expf(p_s - pn);
        aa = e1 * aa + e2 * a_s;
        bb = e1 * bb + e2 * b_s;
        pp = pn;
    }
}

__global__ __launch_bounds__(256) void wkv_out(const float* __restrict__ k,
                                               const float* __restrict__ v,
                                               const bf16* __restrict__ sr,
                                               const float* __restrict__ decay,
                                               const float* __restrict__ first,
                                               const float* __restrict__ ia,
                                               const float* __restrict__ ib,
                                               const float* __restrict__ ip,
                                               bf16* __restrict__ out)
{
    int idx = blockIdx.x * 256 + threadIdx.x;   // (b*NSEG+seg)*C + c
    int c   = idx & (C_DIM - 1);
    int bs  = idx >> 10;
    int seg = bs & (NSEG - 1);
    int b   = bs >> 5;
    float w = -__expf(decay[c]);
    float u = first[c];
    float aa = ia[idx], bb = ib[idx], pp = ip[idx];
    size_t base = ((size_t)b * T_DIM + (size_t)seg * SEGL) * C_DIM + c;
    for (int t = 0; t < SEGL; ++t) {
        size_t off = base + (size_t)t * C_DIM;
        float kk = k[off], vv = v[off];
        float ww = u + kk;
        float p  = fmaxf(pp, ww);
        float e1 = __expf(pp - p);
        float e2 = __expf(ww - p);
        float o  = (e1 * aa + e2 * vv) / (e1 * bb + e2);
        out[off] = (bf16)((float)sr[off] * o);
        float ww2 = pp + w;
        float p2  = fmaxf(ww2, kk);
        float e1b = __expf(ww2 - p2);
        float e2b = __expf(kk - p2);
        aa = e1b * aa + e2b * vv;
        bb = e1b * bb + e2b;
        pp = p2;
    }
}

// ---------------------------------------------------------------------------
// Orchestration. Workspace (byte offsets, 173 MiB peak):
//   [0,26M)    bf16 weights
//   [26,74M)   bf16 acts: xk xv xr -> rwkv | xk2 xr2 sr2
//   [74,170M)  fp32 k (32M), v (32M), sr_b bf16 (16M @138M), kk_b (64M @106M)
//   [170,173M) WKV scan scratch: 6 x 512 KiB
// ---------------------------------------------------------------------------
extern "C" void kernel_launch(void* const* d_in, const int* in_sizes, int n_in,
                              void* d_out, int out_size, void* d_ws, size_t ws_size,
                              hipStream_t stream)
{
    const float* x          = (const float*)d_in[0];
    const float* ln1_w      = (const float*)d_in[1];
    const float* ln1_b      = (const float*)d_in[2];
    const float* ln2_w      = (const float*)d_in[3];
    const float* ln2_b      = (const float*)d_in[4];
    const float* time_decay = (const float*)d_in[5];
    const float* time_first = (const float*)d_in[6];
    const float* tmk        = (const float*)d_in[7];
    const float* tmv        = (const float*)d_in[8];
    const float* tmr        = (const float*)d_in[9];
    const float* att_kw     = (const float*)d_in[10];
    const float* att_vw     = (const float*)d_in[11];
    const float* att_rw     = (const float*)d_in[12];
    const float* att_ow     = (const float*)d_in[13];
    const float* f_tmk      = (const float*)d_in[14];
    const float* f_tmr      = (const float*)d_in[15];
    const float* f_kw       = (const float*)d_in[16];
    const float* f_rw       = (const float*)d_in[17];
    const float* f_vw       = (const float*)d_in[18];
    float* out = (float*)d_out;

    char* W8 = (char*)d_ws;
    bf16* kw_b  = (bf16*)(W8 + 0 * MB);
    bf16* vw_b  = (bf16*)(W8 + 2 * MB);
    bf16* rw_b  = (bf16*)(W8 + 4 * MB);
    bf16* ow_b  = (bf16*)(W8 + 6 * MB);
    bf16* fkw_b = (bf16*)(W8 + 8 * MB);
    bf16* frw_b = (bf16*)(W8 + 16 * MB);
    bf16* fvw_b = (bf16*)(W8 + 18 * MB);

    bf16*  xk_b   = (bf16*)(W8 + 26 * MB);
    bf16*  xv_b   = (bf16*)(W8 + 42 * MB);
    bf16*  xr_b   = (bf16*)(W8 + 58 * MB);
    bf16*  rwkv_b = xk_b;
    bf16*  xk2_b  = (bf16*)(W8 + 26 * MB);
    bf16*  xr2_b  = (bf16*)(W8 + 42 * MB);
    bf16*  sr2_b  = (bf16*)(W8 + 58 * MB);
    float* kbuf   = (float*)(W8 + 74 * MB);
    float* vbuf   = (float*)(W8 + 106 * MB);
    bf16*  srb_b  = (bf16*)(W8 + 138 * MB);     // 16 MiB
    bf16*  kk_b   = (bf16*)(W8 + 106 * MB);     // 64 MiB, overlaps vbuf; kk is
    // written only AFTER wkv_out has consumed kbuf/vbuf (ChannelMix phase).

    size_t KB512 = (size_t)512 * 1024;
    float* sc_a = (float*)(W8 + 170 * MB);
    float* sc_b = (float*)(W8 + 170 * MB + 1 * KB512);
    float* sc_p = (float*)(W8 + 170 * MB + 2 * KB512);
    float* in_a = (float*)(W8 + 170 * MB + 3 * KB512);
    float* in_b = (float*)(W8 + 170 * MB + 4 * KB512);
    float* in_p = (float*)(W8 + 170 * MB + 5 * KB512);

    // single-dispatch weight conversion
    int nC4 = C_DIM * C_DIM / 4, nF4 = FFN_DIM * C_DIM / 4;
    W7 w7;
    const float* srcs[7] = { att_kw, att_vw, att_rw, att_ow, f_kw, f_rw, f_vw };
    bf16*        dsts[7] = { kw_b, vw_b, rw_b, ow_b, fkw_b, frw_b, fvw_b };
    int          cnts[7] = { nC4, nC4, nC4, nC4, nF4, nC4, nF4 };
    int cum = 0;
    for (int i = 0; i < 7; ++i) { w7.s[i] = srcs[i]; w7.d[i] = dsts[i]; w7.cum[i] = cum; cum += cnts[i]; }
    w7.cum[7] = cum;                                   // 3407872, /256 = 13312
    f2b7_kernel<<<cum / 256, 256, 0, stream>>>(w7);

    int segGrid = B_DIM * NSEG * C_DIM / 256;   // 512

    auto launch = [&](const bf16* A, const bf16* W, void* Y, const float* X2,
                      const bf16* S, int N, int K, int epi, int obf) {
        GemmArgs p; p.A = A; p.W = W; p.Y = Y; p.X2 = X2; p.S = S;
        p.N = N; p.K = K; p.epi = epi; p.outBf16 = obf;
        int grid = (NROWS / 256) * (N / 128);
        gemm_p<<<grid, 512, 0, stream>>>(p);
    };

    // --- TimeMix ---
    lnmix_kernel<true><<<NROWS, 256, 0, stream>>>(x, ln1_w, ln1_b, tmk, tmv, tmr,
                                                  xk_b, xv_b, xr_b);
    launch(xk_b, kw_b, kbuf,  nullptr, nullptr, C_DIM, C_DIM, EPI_NONE, 0);
    launch(xv_b, vw_b, vbuf,  nullptr, nullptr, C_DIM, C_DIM, EPI_NONE, 0);
    launch(xr_b, rw_b, srb_b, nullptr, nullptr, C_DIM, C_DIM, EPI_SIG,  1);
    wkv_seg<<<segGrid, 256, 0, stream>>>(kbuf, vbuf, time_decay, sc_a, sc_b, sc_p);
    wkv_comb<<<B_DIM * C_DIM / 256, 256, 0, stream>>>(sc_a, sc_b, sc_p, time_decay, in_a, in_b, in_p);
    wkv_out<<<segGrid, 256, 0, stream>>>(kbuf, vbuf, srb_b, time_decay, time_first,
                                         in_a, in_b, in_p, rwkv_b);
    launch(rwkv_b, ow_b, out, x, nullptr, C_DIM, C_DIM, EPI_ADD, 0);

    // --- ChannelMix ---
    lnmix_kernel<false><<<NROWS, 256, 0, stream>>>(out, ln2_w, ln2_b, f_tmk, nullptr, f_tmr,
                                                   xk2_b, nullptr, xr2_b);
    launch(xr2_b, frw_b, sr2_b, nullptr, nullptr, C_DIM,   C_DIM, EPI_SIG,   1);
    {   // FFN-up on the 256x256 kernel: 32 x 16 = 512 blocks
        GemmArgs p; p.A = xk2_b; p.W = fkw_b; p.Y = kk_b; p.X2 = nullptr; p.S = nullptr;
        p.N = FFN_DIM; p.K = C_DIM; p.epi = EPI_RELU2; p.outBf16 = 1;
        gemm_w<<<(NROWS / 256) * (FFN_DIM / 256), 512, 0, stream>>>(p);
    }
    launch(kk_b,  fvw_b, out,   out,     sr2_b,   C_DIM, FFN_DIM, EPI_SCALEADD, 0);
}